// Round 1
// baseline (248.502 us; speedup 1.0000x reference)
//
#include <hip/hip_runtime.h>

// Problem: BERTEmbedding — out[b,v,e] = (s0*flux_w[v,e]+flux_b[v,e])
//                                     + (s2*time_w[v,e]+time_b[v,e])
//                                     + interleaved sin/cos PE of s1
// B=16, V=4096, E=768, all fp32.
#define BB 16
#define VV 4096
#define EE 768
#define E4 (EE / 4)   // 192 float4 columns per row

// clang ext vector => real 16B loads/stores (HIP float4 is a struct; the
// builtin nontemporal store wants a native vector type).
typedef float f4 __attribute__((ext_vector_type(4)));

// One thread owns a (v, e4) column: loads the 4 weight/bias float4s ONCE,
// then loops over all B batch rows. This guarantees each weight byte is
// fetched from HBM exactly once (no reliance on L3 absorbing a 16x re-read)
// while keeping stores perfectly coalesced (consecutive lanes -> consecutive e).
__global__ __launch_bounds__(256) void bert_embed_kernel(
    const float* __restrict__ seq,     // [B, V, 3]
    const float* __restrict__ flux_w,  // [V, E]
    const float* __restrict__ flux_b,  // [V, E]
    const float* __restrict__ time_w,  // [V, E]
    const float* __restrict__ time_b,  // [V, E]
    float* __restrict__ out)           // [B, V, E]
{
    int tid = blockIdx.x * blockDim.x + threadIdx.x;   // [0, VV*E4)
    int e4  = tid % E4;
    int v   = tid / E4;
    // 192 = 3*64: every wave lies entirely inside one v-row, so v is
    // wave-uniform. Force it scalar so the sequence loads scalarize.
    v = __builtin_amdgcn_readfirstlane(v);

    const size_t we = (size_t)v * EE + (size_t)e4 * 4;
    f4 fw = *(const f4*)(flux_w + we);
    f4 fb = *(const f4*)(flux_b + we);
    f4 tw = *(const f4*)(time_w + we);
    f4 tb = *(const f4*)(time_b + we);

    // div_term[i] = exp(2i * (-ln(10000)/E)); this thread needs pair indices
    // i0 = 2*e4 (-> elements 4e4, 4e4+1) and i1 = 2*e4+1 (-> 4e4+2, 4e4+3).
    const float C1 = -0.011992630692677323f;  // -ln(10000)/768
    float a0 = (float)(4 * e4) * C1;
    float d0 = __expf(a0);
    float d1 = __expf(a0 + 2.0f * C1);

    const float* sp = seq + (size_t)v * 3;   // scalar (wave-uniform) address
    float* op = out + we;

#pragma unroll
    for (int b = 0; b < BB; ++b) {
        float s0 = sp[0];   // flux channel
        float s1 = sp[1];   // passend channel
        float s2 = sp[2];   // time channel

        float sn0, cs0, sn1, cs1;
        __sincosf(s1 * d0, &sn0, &cs0);
        __sincosf(s1 * d1, &sn1, &cs1);

        f4 o;
        o.x = fmaf(s0, fw.x, fb.x) + fmaf(s2, tw.x, tb.x) + sn0;
        o.y = fmaf(s0, fw.y, fb.y) + fmaf(s2, tw.y, tb.y) + cs0;
        o.z = fmaf(s0, fw.z, fb.z) + fmaf(s2, tw.z, tb.z) + sn1;
        o.w = fmaf(s0, fw.w, fb.w) + fmaf(s2, tw.w, tb.w) + cs1;

        // Output is never re-read: bypass L2 so it doesn't thrash the
        // cached sequence data.
        __builtin_nontemporal_store(o, (f4*)op);

        sp += (size_t)VV * 3;      // next batch row of sequence
        op += (size_t)VV * EE;     // next batch slab of output
    }
}

extern "C" void kernel_launch(void* const* d_in, const int* in_sizes, int n_in,
                              void* d_out, int out_size, void* d_ws, size_t ws_size,
                              hipStream_t stream) {
    const float* seq = (const float*)d_in[0];
    const float* fw  = (const float*)d_in[1];
    const float* fb  = (const float*)d_in[2];
    const float* tw  = (const float*)d_in[3];
    const float* tb  = (const float*)d_in[4];
    float* out = (float*)d_out;

    const int total_threads = VV * E4;          // 786,432
    const int block = 256;
    const int grid = total_threads / block;     // 3,072 blocks (12/CU)

    bert_embed_kernel<<<grid, block, 0, stream>>>(seq, fw, fb, tw, tb, out);
}

// Round 2
// 246.475 us; speedup vs baseline: 1.0082x; 1.0082x over previous
//
#include <hip/hip_runtime.h>

// BERTEmbedding: out[b,v,e] = (s0*flux_w[v,e] + flux_b[v,e])
//                           + (s2*time_w[v,e] + time_b[v,e])
//                           + PE(s1)[e]   (interleaved sin/cos)
// B=16, V=4096, E=768, fp32.
#define BB 16
#define VV 4096
#define EE 768
#define E4 (EE / 4)   // 192 float4 columns per row

typedef float f4 __attribute__((ext_vector_type(4)));

// One thread owns a (v, e4) column: weight/bias float4s are loaded from HBM
// exactly once into registers, then the thread loops over all B=16 batch rows.
// Stores stay perfectly coalesced (consecutive lanes -> consecutive e).
// 192 float4-threads per v-row = exactly 3 waves, so v is wave-uniform ->
// readfirstlane scalarizes the sequence loads (s_load through K$).
__global__ __launch_bounds__(256) void bert_embed_kernel(
    const float* __restrict__ seq,     // [B, V, 3]
    const float* __restrict__ flux_w,  // [V, E]
    const float* __restrict__ flux_b,  // [V, E]
    const float* __restrict__ time_w,  // [V, E]
    const float* __restrict__ time_b,  // [V, E]
    float* __restrict__ out)           // [B, V, E]
{
    int tid = blockIdx.x * blockDim.x + threadIdx.x;   // [0, VV*E4)
    int e4  = tid % E4;
    int v   = __builtin_amdgcn_readfirstlane(tid / E4);

    const size_t we = (size_t)v * EE + (size_t)e4 * 4;
    f4 fw = *(const f4*)(flux_w + we);
    f4 tw = *(const f4*)(time_w + we);
    f4 fb = *(const f4*)(flux_b + we);
    f4 tb = *(const f4*)(time_b + we);
    f4 cb = fb + tb;   // combined bias: out = s0*fw + s2*tw + cb + pe

    // div_term[i] = exp(2i * (-ln(10000)/E)). This thread needs pair indices
    // 2*e4 (-> elements 4e4, 4e4+1) and 2*e4+1 (-> 4e4+2, 4e4+3).
    // Fold 1/(2*pi) in: v_sin_f32/v_cos_f32 take REVOLUTIONS (cdna4_isa §3).
    // |s1| <~ 5 rad -> |rev| < 1, well inside the accurate range.
    const float C1     = -0.011992630692677323f;   // -ln(10000)/768
    const float INV2PI = 0.15915494309189535f;
    float d0 = __expf((float)(4 * e4) * C1) * INV2PI;
    float d1 = __expf((float)(4 * e4 + 2) * C1) * INV2PI;

    const float* sp = seq + (size_t)v * 3;   // wave-uniform (scalar) address
    float* op = out + we;

#pragma unroll
    for (int b = 0; b < BB; ++b) {
        float s0 = sp[0];   // flux channel
        float s1 = sp[1];   // passend channel
        float s2 = sp[2];   // time channel

        float r0  = s1 * d0;
        float r1  = s1 * d1;
        float sn0 = __builtin_amdgcn_sinf(r0);   // v_sin_f32 (revolutions)
        float cs0 = __builtin_amdgcn_cosf(r0);
        float sn1 = __builtin_amdgcn_sinf(r1);
        float cs1 = __builtin_amdgcn_cosf(r1);

        f4 o;
        o.x = fmaf(s0, fw.x, fmaf(s2, tw.x, cb.x)) + sn0;
        o.y = fmaf(s0, fw.y, fmaf(s2, tw.y, cb.y)) + cs0;
        o.z = fmaf(s0, fw.z, fmaf(s2, tw.z, cb.z)) + sn1;
        o.w = fmaf(s0, fw.w, fmaf(s2, tw.w, cb.w)) + cs1;
        *(f4*)op = o;

        sp += (size_t)VV * 3;      // next batch row of sequence
        op += (size_t)VV * EE;     // next batch slab of output
    }
}

extern "C" void kernel_launch(void* const* d_in, const int* in_sizes, int n_in,
                              void* d_out, int out_size, void* d_ws, size_t ws_size,
                              hipStream_t stream) {
    const float* seq = (const float*)d_in[0];
    const float* fw  = (const float*)d_in[1];
    const float* fb  = (const float*)d_in[2];
    const float* tw  = (const float*)d_in[3];
    const float* tb  = (const float*)d_in[4];
    float* out = (float*)d_out;

    const int total_threads = VV * E4;        // 786,432
    const int block = 256;
    const int grid  = total_threads / block;  // 3,072 blocks

    bert_embed_kernel<<<grid, block, 0, stream>>>(seq, fw, fb, tw, tb, out);
}